// Round 1
// baseline (580.489 us; speedup 1.0000x reference)
//
#include <hip/hip_runtime.h>
#include <hip/hip_bf16.h>

#define B_ 4
#define T_ 2048
#define C_ 1024
#define H_ 16
#define D_ 64
#define M_ (B_*T_)   // 8192

typedef __bf16 bf16x8 __attribute__((ext_vector_type(8)));
typedef float  f32x4  __attribute__((ext_vector_type(4)));

__device__ __forceinline__ unsigned short f2bf(float f) {
  unsigned u = __builtin_bit_cast(unsigned, f);
  u += 0x7FFF + ((u >> 16) & 1);   // round-to-nearest-even
  return (unsigned short)(u >> 16);
}
__device__ __forceinline__ float bf2f(unsigned short h) {
  unsigned u = ((unsigned)h) << 16;
  return __builtin_bit_cast(float, u);
}

__device__ __forceinline__ void gload_lds16(const void* g, void* l) {
  __builtin_amdgcn_global_load_lds(
      (const __attribute__((address_space(1))) void*)g,
      (__attribute__((address_space(3))) void*)l, 16, 0, 0);
}

// ---------------- conversion: f32 -> bf16 (vectorized) ----------------
__global__ void cvt_f32_bf16(const float* __restrict__ in,
                             unsigned short* __restrict__ out, int n4) {
  int i = blockIdx.x * blockDim.x + threadIdx.x;
  if (i < n4) {
    float4 v = ((const float4*)in)[i];
    ushort4 o;
    o.x = f2bf(v.x); o.y = f2bf(v.y); o.z = f2bf(v.z); o.w = f2bf(v.w);
    ((ushort4*)out)[i] = o;
  }
}

// ------------- weight transpose + convert: W[K][N] f32 -> Wt[N][K] bf16 -------------
__global__ void transpose_cvt(const float* __restrict__ w0, const float* __restrict__ w1,
                              const float* __restrict__ w2, const float* __restrict__ w3,
                              unsigned short* __restrict__ t0, unsigned short* __restrict__ t1,
                              unsigned short* __restrict__ t2, unsigned short* __restrict__ t3) {
  __shared__ float tile[32][33];
  const float* src; unsigned short* dst;
  switch (blockIdx.z) {
    case 0: src = w0; dst = t0; break;
    case 1: src = w1; dst = t1; break;
    case 2: src = w2; dst = t2; break;
    default: src = w3; dst = t3; break;
  }
  int bx = blockIdx.x * 32;  // n base
  int by = blockIdx.y * 32;  // k base
  int tx = threadIdx.x, ty = threadIdx.y;
  #pragma unroll
  for (int j = 0; j < 4; ++j)
    tile[ty + 8*j][tx] = src[(size_t)(by + ty + 8*j) * C_ + bx + tx];
  __syncthreads();
  #pragma unroll
  for (int j = 0; j < 4; ++j)
    dst[(size_t)(bx + ty + 8*j) * C_ + by + tx] = f2bf(tile[tx][ty + 8*j]);
}

// ---------------- bf16 MFMA GEMM: A[M][K] * Bt[N][K]^T + bias ----------------
// MODE 0: store bf16, head-split [B][H][T][D]
// MODE 1: store bf16, head-split transposed [B][H][D][T]  (for V)
// MODE 2: store f32 [M][N]                                 (final output)
template<int MODE>
__global__ __launch_bounds__(256, 2)
void gemm_bf16(const unsigned short* __restrict__ A,
               const unsigned short* __restrict__ Bt,
               const float* __restrict__ bias,
               void* __restrict__ Cout, int K, int N)
{
  __shared__ unsigned short lsA[128 * 64];
  __shared__ unsigned short lsB[128 * 64];
  const int wave = threadIdx.x >> 6;
  const int lane = threadIdx.x & 63;
  const int rowBase = blockIdx.y * 128;
  const int colBase = blockIdx.x * 128;
  const int rowOff = (wave >> 1) * 64;
  const int colOff = (wave & 1) * 64;
  const int lr = lane & 15;
  const int lg = lane >> 4;

  f32x4 acc[4][4] = {};

  const int chunkRow = lane >> 3;                       // 0..7 within chunk
  const int srcColE  = (((lane & 7) ^ (lane >> 3)) * 8); // inverse-swizzled source column (elems)

  for (int k0 = 0; k0 < K; k0 += 64) {
    #pragma unroll
    for (int c = 0; c < 4; ++c) {
      int chunk = c * 4 + wave;          // 0..15, covers rows chunk*8..+7
      int r = chunk * 8 + chunkRow;
      gload_lds16(A  + (size_t)(rowBase + r) * K + k0 + srcColE, &lsA[chunk * 512]);
      gload_lds16(Bt + (size_t)(colBase + r) * K + k0 + srcColE, &lsB[chunk * 512]);
    }
    __syncthreads();
    #pragma unroll
    for (int kk = 0; kk < 2; ++kk) {
      bf16x8 af[4], bfr[4];
      const int kbyte = (kk * 32 + lg * 8) * 2;
      #pragma unroll
      for (int m = 0; m < 4; ++m) {
        int row = rowOff + m * 16 + lr;
        af[m] = *(const bf16x8*)((const char*)lsA + row * 128 + (kbyte ^ ((row & 7) << 4)));
      }
      #pragma unroll
      for (int n = 0; n < 4; ++n) {
        int row = colOff + n * 16 + lr;
        bfr[n] = *(const bf16x8*)((const char*)lsB + row * 128 + (kbyte ^ ((row & 7) << 4)));
      }
      #pragma unroll
      for (int m = 0; m < 4; ++m)
        #pragma unroll
        for (int n = 0; n < 4; ++n)
          acc[m][n] = __builtin_amdgcn_mfma_f32_16x16x32_bf16(af[m], bfr[n], acc[m][n], 0, 0, 0);
    }
    __syncthreads();
  }

  // epilogue: C row = rowBase+rowOff+m*16+(lg*4+j), col = colBase+colOff+n*16+lr
  #pragma unroll
  for (int m = 0; m < 4; ++m) {
    int row0 = rowBase + rowOff + m * 16 + lg * 4;
    #pragma unroll
    for (int n = 0; n < 4; ++n) {
      int col = colBase + colOff + n * 16 + lr;
      float bs = bias[col];
      if (MODE == 1) {
        // V transposed store: 4 consecutive t values -> one ushort4
        int b = row0 >> 11, t = row0 & 2047;
        int h = col >> 6, d = col & 63;
        ushort4 o;
        o.x = f2bf(acc[m][n][0] + bs);
        o.y = f2bf(acc[m][n][1] + bs);
        o.z = f2bf(acc[m][n][2] + bs);
        o.w = f2bf(acc[m][n][3] + bs);
        *(ushort4*)((unsigned short*)Cout + (((size_t)b * H_ + h) * D_ + d) * T_ + t) = o;
      } else {
        #pragma unroll
        for (int j = 0; j < 4; ++j) {
          float v = acc[m][n][j] + bs;
          int r = row0 + j;
          if (MODE == 2) {
            ((float*)Cout)[(size_t)r * N + col] = v;
          } else {
            int b = r >> 11, t = r & 2047;
            int h = col >> 6, d = col & 63;
            ((unsigned short*)Cout)[((((size_t)b * H_ + h) * T_ + t) << 6) + d] = f2bf(v);
          }
        }
      }
    }
  }
}

// ---------------- causal flash attention ----------------
// q,k: [B][H][T][D] bf16 ; vt: [B][H][D][T] bf16 ; y: [B][T][C] bf16
__global__ __launch_bounds__(256, 4)
void attn_kernel(const unsigned short* __restrict__ q,
                 const unsigned short* __restrict__ k,
                 const unsigned short* __restrict__ vt,
                 unsigned short* __restrict__ y)
{
  __shared__ unsigned short pT[4][16 * 40];  // per-wave P transpose buffer (row stride 40 -> 80B, 16B-aligned)
  const int wave = threadIdx.x >> 6;
  const int lane = threadIdx.x & 63;
  const int bh = blockIdx.y;
  const int b = bh >> 4, h = bh & 15;
  const int q0 = blockIdx.x * 64 + wave * 16;
  const unsigned short* qh = q  + (size_t)bh * T_ * D_;
  const unsigned short* kh = k  + (size_t)bh * T_ * D_;
  const unsigned short* vh = vt + (size_t)bh * D_ * T_;
  const int lr = lane & 15;
  const int lg = lane >> 4;

  // Q fragments (row = lr, k = kk*32 + lg*8 + e)
  bf16x8 aq[2];
  #pragma unroll
  for (int kk = 0; kk < 2; ++kk)
    aq[kk] = *(const bf16x8*)(qh + (size_t)(q0 + lr) * D_ + kk * 32 + lg * 8);

  f32x4 o[4] = {};
  float mrow[4], lsum[4];
  #pragma unroll
  for (int j = 0; j < 4; ++j) { mrow[j] = -INFINITY; lsum[j] = 0.f; }

  unsigned short* myP = pT[wave];
  const int nkb = (q0 + 47) >> 5;   // ceil((q0+16)/32) key-blocks of 32

  for (int kb = 0; kb < nkb; ++kb) {
    const int n0 = kb * 32;
    f32x4 s[2];
    #pragma unroll
    for (int g = 0; g < 2; ++g) {
      const unsigned short* kr = kh + (size_t)(n0 + g * 16 + lr) * D_ + lg * 8;
      bf16x8 bk0 = *(const bf16x8*)(kr);
      bf16x8 bk1 = *(const bf16x8*)(kr + 32);
      f32x4 sv = {};
      sv = __builtin_amdgcn_mfma_f32_16x16x32_bf16(aq[0], bk0, sv, 0, 0, 0);
      sv = __builtin_amdgcn_mfma_f32_16x16x32_bf16(aq[1], bk1, sv, 0, 0, 0);
      s[g] = sv;
    }
    // scale + causal mask
    #pragma unroll
    for (int g = 0; g < 2; ++g)
      #pragma unroll
      for (int j = 0; j < 4; ++j) {
        int qrow = q0 + lg * 4 + j;
        int kcol = n0 + g * 16 + lr;
        float v = s[g][j] * 0.125f;
        s[g][j] = (kcol <= qrow) ? v : -INFINITY;
      }
    // online softmax
    float corr[4];
    #pragma unroll
    for (int j = 0; j < 4; ++j) {
      float x = fmaxf(s[0][j], s[1][j]);
      #pragma unroll
      for (int off = 1; off < 16; off <<= 1) x = fmaxf(x, __shfl_xor(x, off));
      float mnew = fmaxf(mrow[j], x);
      corr[j] = __expf(mrow[j] - mnew);
      mrow[j] = mnew;
      float p0 = __expf(s[0][j] - mnew);
      float p1 = __expf(s[1][j] - mnew);
      unsigned short u0 = f2bf(p0), u1 = f2bf(p1);
      myP[(lg * 4 + j) * 40 + lr]      = u0;
      myP[(lg * 4 + j) * 40 + 16 + lr] = u1;
      float ps = bf2f(u0) + bf2f(u1);   // sum what PV will actually use
      #pragma unroll
      for (int off = 1; off < 16; off <<= 1) ps += __shfl_xor(ps, off);
      lsum[j] = lsum[j] * corr[j] + ps;
    }
    #pragma unroll
    for (int n = 0; n < 4; ++n)
      #pragma unroll
      for (int j = 0; j < 4; ++j) o[n][j] *= corr[j];
    // PV: A = P (row=lr, k=lg*8+e over 32 keys), B = V (col=lr d, k=keys)
    bf16x8 ap = *(const bf16x8*)(myP + lr * 40 + lg * 8);
    #pragma unroll
    for (int n = 0; n < 4; ++n) {
      bf16x8 bv = *(const bf16x8*)(vh + (size_t)(n * 16 + lr) * T_ + n0 + lg * 8);
      o[n] = __builtin_amdgcn_mfma_f32_16x16x32_bf16(ap, bv, o[n], 0, 0, 0);
    }
  }

  // normalize + store y[B][T][C]
  #pragma unroll
  for (int n = 0; n < 4; ++n)
    #pragma unroll
    for (int j = 0; j < 4; ++j) {
      int t = q0 + lg * 4 + j;
      float val = o[n][j] / lsum[j];
      y[((size_t)b * T_ + t) * C_ + h * D_ + n * 16 + lr] = f2bf(val);
    }
}

extern "C" void kernel_launch(void* const* d_in, const int* in_sizes, int n_in,
                              void* d_out, int out_size, void* d_ws, size_t ws_size,
                              hipStream_t stream) {
  const float* x  = (const float*)d_in[0];
  const float* Wq = (const float*)d_in[1];
  const float* bq = (const float*)d_in[2];
  const float* Wk = (const float*)d_in[3];
  const float* bk = (const float*)d_in[4];
  const float* Wv = (const float*)d_in[5];
  const float* bv = (const float*)d_in[6];
  const float* Wp = (const float*)d_in[7];
  const float* bp = (const float*)d_in[8];
  float* out = (float*)d_out;

  char* ws = (char*)d_ws;
  unsigned short* xb  = (unsigned short*)ws; ws += (size_t)M_ * C_ * 2;
  unsigned short* wqt = (unsigned short*)ws; ws += (size_t)C_ * C_ * 2;
  unsigned short* wkt = (unsigned short*)ws; ws += (size_t)C_ * C_ * 2;
  unsigned short* wvt = (unsigned short*)ws; ws += (size_t)C_ * C_ * 2;
  unsigned short* wpt = (unsigned short*)ws; ws += (size_t)C_ * C_ * 2;
  unsigned short* qb  = (unsigned short*)ws; ws += (size_t)M_ * C_ * 2;
  unsigned short* kb  = (unsigned short*)ws; ws += (size_t)M_ * C_ * 2;
  unsigned short* vtb = (unsigned short*)ws; ws += (size_t)M_ * C_ * 2;
  unsigned short* yb  = (unsigned short*)ws; ws += (size_t)M_ * C_ * 2;

  // 1) convert x to bf16
  cvt_f32_bf16<<<dim3((M_ * C_ / 4 + 255) / 256), dim3(256), 0, stream>>>(x, xb, M_ * C_ / 4);
  // 2) transpose+convert all 4 weights
  transpose_cvt<<<dim3(32, 32, 4), dim3(32, 8), 0, stream>>>(Wq, Wk, Wv, Wp, wqt, wkt, wvt, wpt);
  // 3) projections
  dim3 ggrid(C_ / 128, M_ / 128);
  gemm_bf16<0><<<ggrid, dim3(256), 0, stream>>>(xb, wqt, bq, qb, C_, C_);
  gemm_bf16<0><<<ggrid, dim3(256), 0, stream>>>(xb, wkt, bk, kb, C_, C_);
  gemm_bf16<1><<<ggrid, dim3(256), 0, stream>>>(xb, wvt, bv, vtb, C_, C_);
  // 4) causal flash attention
  attn_kernel<<<dim3(T_ / 64, B_ * H_), dim3(256), 0, stream>>>(qb, kb, vtb, yb);
  // 5) output projection (f32 out)
  gemm_bf16<2><<<ggrid, dim3(256), 0, stream>>>(yb, wpt, bp, out, C_, C_);
}

// Round 2
// 449.630 us; speedup vs baseline: 1.2910x; 1.2910x over previous
//
#include <hip/hip_runtime.h>
#include <hip/hip_bf16.h>

#define B_ 4
#define T_ 2048
#define C_ 1024
#define H_ 16
#define D_ 64
#define M_ (B_*T_)   // 8192

typedef __bf16 bf16x8 __attribute__((ext_vector_type(8)));
typedef float  f32x4  __attribute__((ext_vector_type(4)));
typedef float  f32x16 __attribute__((ext_vector_type(16)));

__device__ __forceinline__ unsigned short f2bf(float f) {
  unsigned u = __builtin_bit_cast(unsigned, f);
  u += 0x7FFF + ((u >> 16) & 1);   // round-to-nearest-even
  return (unsigned short)(u >> 16);
}

__device__ __forceinline__ void gload_lds16(const void* g, void* l) {
  __builtin_amdgcn_global_load_lds(
      (const __attribute__((address_space(1))) void*)g,
      (__attribute__((address_space(3))) void*)l, 16, 0, 0);
}

// ---------------- conversion: f32 -> bf16 (vectorized) ----------------
__global__ void cvt_f32_bf16(const float* __restrict__ in,
                             unsigned short* __restrict__ out, int n4) {
  int i = blockIdx.x * blockDim.x + threadIdx.x;
  if (i < n4) {
    float4 v = ((const float4*)in)[i];
    ushort4 o;
    o.x = f2bf(v.x); o.y = f2bf(v.y); o.z = f2bf(v.z); o.w = f2bf(v.w);
    ((ushort4*)out)[i] = o;
  }
}

// ------------- weight transpose + convert: W[K][N] f32 -> Wt[N][K] bf16 -------------
__global__ void transpose_cvt(const float* __restrict__ w0, const float* __restrict__ w1,
                              const float* __restrict__ w2, const float* __restrict__ w3,
                              unsigned short* __restrict__ t0, unsigned short* __restrict__ t1,
                              unsigned short* __restrict__ t2, unsigned short* __restrict__ t3) {
  __shared__ float tile[32][33];
  const float* src; unsigned short* dst;
  switch (blockIdx.z) {
    case 0: src = w0; dst = t0; break;
    case 1: src = w1; dst = t1; break;
    case 2: src = w2; dst = t2; break;
    default: src = w3; dst = t3; break;
  }
  int bx = blockIdx.x * 32;  // n base
  int by = blockIdx.y * 32;  // k base
  int tx = threadIdx.x, ty = threadIdx.y;
  #pragma unroll
  for (int j = 0; j < 4; ++j)
    tile[ty + 8*j][tx] = src[(size_t)(by + ty + 8*j) * C_ + bx + tx];
  __syncthreads();
  #pragma unroll
  for (int j = 0; j < 4; ++j)
    dst[(size_t)(bx + ty + 8*j) * C_ + by + tx] = f2bf(tile[tx][ty + 8*j]);
}

// ---------------- bf16 MFMA GEMM: A[M][K] * Bt[N][K]^T + bias, then *oscale ----------------
// MODE 0: store bf16, head-split [B][H][T][D]
// MODE 1: store bf16, head-split transposed [B][H][D][T]  (for V)
// MODE 2: store f32 [M][N]                                 (final output)
template<int MODE>
__global__ __launch_bounds__(256, 2)
void gemm_bf16(const unsigned short* __restrict__ A,
               const unsigned short* __restrict__ Bt,
               const float* __restrict__ bias,
               void* __restrict__ Cout, int K, int N, float oscale)
{
  __shared__ unsigned short lsA[128 * 64];
  __shared__ unsigned short lsB[128 * 64];
  const int wave = threadIdx.x >> 6;
  const int lane = threadIdx.x & 63;
  const int rowBase = blockIdx.y * 128;
  const int colBase = blockIdx.x * 128;
  const int rowOff = (wave >> 1) * 64;
  const int colOff = (wave & 1) * 64;
  const int lr = lane & 15;
  const int lg = lane >> 4;

  f32x4 acc[4][4] = {};

  const int chunkRow = lane >> 3;
  const int srcColE  = (((lane & 7) ^ (lane >> 3)) * 8);

  for (int k0 = 0; k0 < K; k0 += 64) {
    #pragma unroll
    for (int c = 0; c < 4; ++c) {
      int chunk = c * 4 + wave;
      int r = chunk * 8 + chunkRow;
      gload_lds16(A  + (size_t)(rowBase + r) * K + k0 + srcColE, &lsA[chunk * 512]);
      gload_lds16(Bt + (size_t)(colBase + r) * K + k0 + srcColE, &lsB[chunk * 512]);
    }
    __syncthreads();
    #pragma unroll
    for (int kk = 0; kk < 2; ++kk) {
      bf16x8 af[4], bfr[4];
      const int kbyte = (kk * 32 + lg * 8) * 2;
      #pragma unroll
      for (int m = 0; m < 4; ++m) {
        int row = rowOff + m * 16 + lr;
        af[m] = *(const bf16x8*)((const char*)lsA + row * 128 + (kbyte ^ ((row & 7) << 4)));
      }
      #pragma unroll
      for (int n = 0; n < 4; ++n) {
        int row = colOff + n * 16 + lr;
        bfr[n] = *(const bf16x8*)((const char*)lsB + row * 128 + (kbyte ^ ((row & 7) << 4)));
      }
      #pragma unroll
      for (int m = 0; m < 4; ++m)
        #pragma unroll
        for (int n = 0; n < 4; ++n)
          acc[m][n] = __builtin_amdgcn_mfma_f32_16x16x32_bf16(af[m], bfr[n], acc[m][n], 0, 0, 0);
    }
    __syncthreads();
  }

  #pragma unroll
  for (int m = 0; m < 4; ++m) {
    int row0 = rowBase + rowOff + m * 16 + lg * 4;
    #pragma unroll
    for (int n = 0; n < 4; ++n) {
      int col = colBase + colOff + n * 16 + lr;
      float bs = bias[col];
      if (MODE == 1) {
        int b = row0 >> 11, t = row0 & 2047;
        int h = col >> 6, d = col & 63;
        ushort4 o;
        o.x = f2bf((acc[m][n][0] + bs) * oscale);
        o.y = f2bf((acc[m][n][1] + bs) * oscale);
        o.z = f2bf((acc[m][n][2] + bs) * oscale);
        o.w = f2bf((acc[m][n][3] + bs) * oscale);
        *(ushort4*)((unsigned short*)Cout + (((size_t)b * H_ + h) * D_ + d) * T_ + t) = o;
      } else {
        #pragma unroll
        for (int j = 0; j < 4; ++j) {
          float v = (acc[m][n][j] + bs) * oscale;
          int r = row0 + j;
          if (MODE == 2) {
            ((float*)Cout)[(size_t)r * N + col] = v;
          } else {
            int b = r >> 11, t = r & 2047;
            int h = col >> 6, d = col & 63;
            ((unsigned short*)Cout)[((((size_t)b * H_ + h) * T_ + t) << 6) + d] = f2bf(v);
          }
        }
      }
    }
  }
}

// ---------------- causal flash attention, 32 q-rows/wave, 32x32x16 MFMA ----------------
// q,k: [B][H][T][D] bf16 (q pre-scaled by 1/sqrt(D)) ; vt: [B][H][D][T] bf16 ; y: [B][T][C] bf16
//
// Swapped QK^T: S^T = K·Q^T  (C: col=query=lane&31, row=key_off=(r&3)+8*(r>>2)+4*hi)
// Swapped PV:   O^T = V^T·P^T (C: col=query,        row=d_off  =(r&3)+8*(r>>2)+4*hi)
// The PV contraction uses a k-permutation κ(slot=hi*8+e) = (e&3)+8*(e>>2)+4*hi applied to BOTH
// operands, so P^T B-fragments come straight from the S^T registers (lane-local, in order)
// and V^T A-fragments are two 8B loads per k-step. No LDS, no cross-lane P movement.
__global__ void attn2(const unsigned short* __restrict__ q,
                      const unsigned short* __restrict__ k,
                      const unsigned short* __restrict__ vt,
                      unsigned short* __restrict__ y)
{
  const int wave = threadIdx.x >> 6;
  const int lane = threadIdx.x & 63;
  const int col  = lane & 31;   // query index within tile
  const int hi   = lane >> 5;
  const int bh = blockIdx.y;
  const int b = bh >> 4, h = bh & 15;
  const int q0 = (blockIdx.x * 4 + wave) * 32;
  const unsigned short* qh = q  + (size_t)bh * T_ * D_;
  const unsigned short* kh = k  + (size_t)bh * T_ * D_;
  const unsigned short* vh = vt + (size_t)bh * D_ * T_;

  // Q B-fragments: frag[ks] supplies Q[q0+col][ks*16 + hi*8 + e]
  bf16x8 bqf[4];
  {
    const unsigned short* qrow = qh + (size_t)(q0 + col) * D_ + hi * 8;
    #pragma unroll
    for (int ks = 0; ks < 4; ++ks) bqf[ks] = *(const bf16x8*)(qrow + ks * 16);
  }

  f32x16 ot[2] = {};           // O^T accumulators: d = dt*32 + (r&3)+8*(r>>2)+4*hi
  float m = -INFINITY, l = 0.f;

  union U8 { ushort4 h[2]; bf16x8 f; };

  auto kv_step = [&](int n0, bool masked) {
    // ---- QK^T ----
    f32x16 st[2];
    #pragma unroll
    for (int tt = 0; tt < 2; ++tt) {
      f32x16 acc = {};
      const unsigned short* krow = kh + (size_t)(n0 + tt * 32 + col) * D_ + hi * 8;
      #pragma unroll
      for (int ks = 0; ks < 4; ++ks) {
        bf16x8 ak = *(const bf16x8*)(krow + ks * 16);
        acc = __builtin_amdgcn_mfma_f32_32x32x16_bf16(ak, bqf[ks], acc, 0, 0, 0);
      }
      st[tt] = acc;
    }
    // ---- causal mask (only in the diagonal block) ----
    if (masked) {
      #pragma unroll
      for (int tt = 0; tt < 2; ++tt)
        #pragma unroll
        for (int r = 0; r < 16; ++r) {
          int key = n0 + tt * 32 + (r & 3) + 8 * (r >> 2) + 4 * hi;
          if (key > q0 + col) st[tt][r] = -INFINITY;
        }
    }
    // ---- online softmax (lane-local: lane owns query q0+col) ----
    float mm[16];
    #pragma unroll
    for (int r = 0; r < 16; ++r) mm[r] = fmaxf(st[0][r], st[1][r]);
    #pragma unroll
    for (int s = 8; s; s >>= 1)
      #pragma unroll
      for (int r = 0; r < s; ++r) mm[r] = fmaxf(mm[r], mm[r + s]);
    float mx = fmaxf(mm[0], __shfl_xor(mm[0], 32));
    float mnew = fmaxf(m, mx);
    float corr = __expf(m - mnew);
    m = mnew;

    bf16x8 pf[4];
    float psum = 0.f;
    #pragma unroll
    for (int tt = 0; tt < 2; ++tt)
      #pragma unroll
      for (int half = 0; half < 2; ++half) {
        bf16x8 w;
        #pragma unroll
        for (int e = 0; e < 8; ++e) {
          float pv = __expf(st[tt][half * 8 + e] - mnew);
          psum += pv;
          w[e] = (__bf16)pv;
        }
        pf[tt * 2 + half] = w;
      }
    psum += __shfl_xor(psum, 32);
    l = l * corr + psum;

    #pragma unroll
    for (int r = 0; r < 16; ++r) { ot[0][r] *= corr; ot[1][r] *= corr; }

    // ---- PV: O^T += V^T · P^T (k-permuted consistently on both sides) ----
    #pragma unroll
    for (int dt = 0; dt < 2; ++dt) {
      const unsigned short* vrow = vh + (size_t)(dt * 32 + col) * T_ + n0 + hi * 4;
      #pragma unroll
      for (int ks = 0; ks < 4; ++ks) {
        U8 av;
        av.h[0] = *(const ushort4*)(vrow + ks * 16);
        av.h[1] = *(const ushort4*)(vrow + ks * 16 + 8);
        ot[dt] = __builtin_amdgcn_mfma_f32_32x32x16_bf16(av.f, pf[ks], ot[dt], 0, 0, 0);
      }
    }
  };

  const int nfull = q0 >> 6;
  for (int kb = 0; kb < nfull; ++kb) kv_step(kb * 64, false);
  kv_step(nfull * 64, true);

  // ---- normalize + store y[B][T][C] ----
  float inv = 1.f / l;
  unsigned short* yrow = y + ((size_t)b * T_ + q0 + col) * C_ + h * D_;
  #pragma unroll
  for (int dt = 0; dt < 2; ++dt)
    #pragma unroll
    for (int a = 0; a < 4; ++a) {
      ushort4 o4;
      o4.x = f2bf(ot[dt][4 * a + 0] * inv);
      o4.y = f2bf(ot[dt][4 * a + 1] * inv);
      o4.z = f2bf(ot[dt][4 * a + 2] * inv);
      o4.w = f2bf(ot[dt][4 * a + 3] * inv);
      *(ushort4*)(yrow + dt * 32 + 8 * a + 4 * hi) = o4;
    }
}

extern "C" void kernel_launch(void* const* d_in, const int* in_sizes, int n_in,
                              void* d_out, int out_size, void* d_ws, size_t ws_size,
                              hipStream_t stream) {
  const float* x  = (const float*)d_in[0];
  const float* Wq = (const float*)d_in[1];
  const float* bq = (const float*)d_in[2];
  const float* Wk = (const float*)d_in[3];
  const float* bk = (const float*)d_in[4];
  const float* Wv = (const float*)d_in[5];
  const float* bv = (const float*)d_in[6];
  const float* Wp = (const float*)d_in[7];
  const float* bp = (const float*)d_in[8];
  float* out = (float*)d_out;

  char* ws = (char*)d_ws;
  unsigned short* xb  = (unsigned short*)ws; ws += (size_t)M_ * C_ * 2;
  unsigned short* wqt = (unsigned short*)ws; ws += (size_t)C_ * C_ * 2;
  unsigned short* wkt = (unsigned short*)ws; ws += (size_t)C_ * C_ * 2;
  unsigned short* wvt = (unsigned short*)ws; ws += (size_t)C_ * C_ * 2;
  unsigned short* wpt = (unsigned short*)ws; ws += (size_t)C_ * C_ * 2;
  unsigned short* qb  = (unsigned short*)ws; ws += (size_t)M_ * C_ * 2;
  unsigned short* kb  = (unsigned short*)ws; ws += (size_t)M_ * C_ * 2;
  unsigned short* vtb = (unsigned short*)ws; ws += (size_t)M_ * C_ * 2;
  unsigned short* yb  = (unsigned short*)ws; ws += (size_t)M_ * C_ * 2;

  cvt_f32_bf16<<<dim3((M_ * C_ / 4 + 255) / 256), dim3(256), 0, stream>>>(x, xb, M_ * C_ / 4);
  transpose_cvt<<<dim3(32, 32, 4), dim3(32, 8), 0, stream>>>(Wq, Wk, Wv, Wp, wqt, wkt, wvt, wpt);

  dim3 ggrid(C_ / 128, M_ / 128);
  const float rsqrtD = 0.125f;  // 1/sqrt(64), folded into Q projection
  gemm_bf16<0><<<ggrid, dim3(256), 0, stream>>>(xb, wqt, bq, qb, C_, C_, rsqrtD);
  gemm_bf16<0><<<ggrid, dim3(256), 0, stream>>>(xb, wkt, bk, kb, C_, C_, 1.f);
  gemm_bf16<1><<<ggrid, dim3(256), 0, stream>>>(xb, wvt, bv, vtb, C_, C_, 1.f);

  attn2<<<dim3(T_ / 128, B_ * H_), dim3(256), 0, stream>>>(qb, kb, vtb, yb);

  gemm_bf16<2><<<ggrid, dim3(256), 0, stream>>>(yb, wpt, bp, out, C_, C_, 1.f);
}

// Round 3
// 229.398 us; speedup vs baseline: 2.5305x; 1.9600x over previous
//
#include <hip/hip_runtime.h>
#include <hip/hip_bf16.h>

#define B_ 4
#define T_ 2048
#define C_ 1024
#define H_ 16
#define D_ 64
#define M_ (B_*T_)   // 8192

typedef __bf16 bf16x8 __attribute__((ext_vector_type(8)));
typedef float  f32x4  __attribute__((ext_vector_type(4)));
typedef float  f32x16 __attribute__((ext_vector_type(16)));

__device__ __forceinline__ unsigned short f2bf(float f) {
  unsigned u = __builtin_bit_cast(unsigned, f);
  u += 0x7FFF + ((u >> 16) & 1);   // round-to-nearest-even
  return (unsigned short)(u >> 16);
}

__device__ __forceinline__ void gload_lds16(const void* g, void* l) {
  __builtin_amdgcn_global_load_lds(
      (const __attribute__((address_space(1))) void*)g,
      (__attribute__((address_space(3))) void*)l, 16, 0, 0);
}

// ---------------- conversion: f32 -> bf16 (vectorized) ----------------
__global__ void cvt_f32_bf16(const float* __restrict__ in,
                             unsigned short* __restrict__ out, int n4) {
  int i = blockIdx.x * blockDim.x + threadIdx.x;
  if (i < n4) {
    float4 v = ((const float4*)in)[i];
    ushort4 o;
    o.x = f2bf(v.x); o.y = f2bf(v.y); o.z = f2bf(v.z); o.w = f2bf(v.w);
    ((ushort4*)out)[i] = o;
  }
}

// ------------- weight transpose + convert: W[K][N] f32 -> Wt[N][K] bf16 -------------
__global__ void transpose_cvt(const float* __restrict__ w0, const float* __restrict__ w1,
                              const float* __restrict__ w2, const float* __restrict__ w3,
                              unsigned short* __restrict__ t0, unsigned short* __restrict__ t1,
                              unsigned short* __restrict__ t2, unsigned short* __restrict__ t3) {
  __shared__ float tile[32][33];
  const float* src; unsigned short* dst;
  switch (blockIdx.z) {
    case 0: src = w0; dst = t0; break;
    case 1: src = w1; dst = t1; break;
    case 2: src = w2; dst = t2; break;
    default: src = w3; dst = t3; break;
  }
  int bx = blockIdx.x * 32;  // n base
  int by = blockIdx.y * 32;  // k base
  int tx = threadIdx.x, ty = threadIdx.y;
  #pragma unroll
  for (int j = 0; j < 4; ++j)
    tile[ty + 8*j][tx] = src[(size_t)(by + ty + 8*j) * C_ + bx + tx];
  __syncthreads();
  #pragma unroll
  for (int j = 0; j < 4; ++j)
    dst[(size_t)(bx + ty + 8*j) * C_ + by + tx] = f2bf(tile[tx][ty + 8*j]);
}

// ---------------- bf16 MFMA GEMM: A[M][K] * Bt[N][K]^T + bias, then *oscale ----------------
// MODE 0: store bf16, head-split [B][H][T][D]
// MODE 1: store bf16, head-split transposed [B][H][D][T] with key-permuted order
//         (t bits 2<->3 swapped within each 16-group) for direct PV A-fragment reads
// MODE 2: store f32 [M][N]                                 (final output)
template<int MODE>
__global__ __launch_bounds__(256, 2)
void gemm_bf16(const unsigned short* __restrict__ A,
               const unsigned short* __restrict__ Bt,
               const float* __restrict__ bias,
               void* __restrict__ Cout, int K, int N, float oscale)
{
  __shared__ unsigned short lsA[128 * 64];
  __shared__ unsigned short lsB[128 * 64];
  const int wave = threadIdx.x >> 6;
  const int lane = threadIdx.x & 63;
  const int rowBase = blockIdx.y * 128;
  const int colBase = blockIdx.x * 128;
  const int rowOff = (wave >> 1) * 64;
  const int colOff = (wave & 1) * 64;
  const int lr = lane & 15;
  const int lg = lane >> 4;

  f32x4 acc[4][4] = {};

  const int chunkRow = lane >> 3;
  const int srcColE  = (((lane & 7) ^ (lane >> 3)) * 8);

  for (int k0 = 0; k0 < K; k0 += 64) {
    #pragma unroll
    for (int c = 0; c < 4; ++c) {
      int chunk = c * 4 + wave;
      int r = chunk * 8 + chunkRow;
      gload_lds16(A  + (size_t)(rowBase + r) * K + k0 + srcColE, &lsA[chunk * 512]);
      gload_lds16(Bt + (size_t)(colBase + r) * K + k0 + srcColE, &lsB[chunk * 512]);
    }
    __syncthreads();
    #pragma unroll
    for (int kk = 0; kk < 2; ++kk) {
      bf16x8 af[4], bfr[4];
      const int kbyte = (kk * 32 + lg * 8) * 2;
      #pragma unroll
      for (int m = 0; m < 4; ++m) {
        int row = rowOff + m * 16 + lr;
        af[m] = *(const bf16x8*)((const char*)lsA + row * 128 + (kbyte ^ ((row & 7) << 4)));
      }
      #pragma unroll
      for (int n = 0; n < 4; ++n) {
        int row = colOff + n * 16 + lr;
        bfr[n] = *(const bf16x8*)((const char*)lsB + row * 128 + (kbyte ^ ((row & 7) << 4)));
      }
      #pragma unroll
      for (int m = 0; m < 4; ++m)
        #pragma unroll
        for (int n = 0; n < 4; ++n)
          acc[m][n] = __builtin_amdgcn_mfma_f32_16x16x32_bf16(af[m], bfr[n], acc[m][n], 0, 0, 0);
    }
    __syncthreads();
  }

  #pragma unroll
  for (int m = 0; m < 4; ++m) {
    int row0 = rowBase + rowOff + m * 16 + lg * 4;
    #pragma unroll
    for (int n = 0; n < 4; ++n) {
      int col = colBase + colOff + n * 16 + lr;
      float bs = bias[col];
      if (MODE == 1) {
        int b = row0 >> 11, t = row0 & 2047;
        int t2 = (t & ~12) | ((t & 4) << 1) | ((t & 8) >> 1);  // key-perm (bits 2<->3)
        int h = col >> 6, d = col & 63;
        ushort4 o;
        o.x = f2bf((acc[m][n][0] + bs) * oscale);
        o.y = f2bf((acc[m][n][1] + bs) * oscale);
        o.z = f2bf((acc[m][n][2] + bs) * oscale);
        o.w = f2bf((acc[m][n][3] + bs) * oscale);
        *(ushort4*)((unsigned short*)Cout + (((size_t)b * H_ + h) * D_ + d) * T_ + t2) = o;
      } else {
        #pragma unroll
        for (int j = 0; j < 4; ++j) {
          float v = (acc[m][n][j] + bs) * oscale;
          int r = row0 + j;
          if (MODE == 2) {
            ((float*)Cout)[(size_t)r * N + col] = v;
          } else {
            int b = r >> 11, t = r & 2047;
            int h = col >> 6, d = col & 63;
            ((unsigned short*)Cout)[((((size_t)b * H_ + h) * T_ + t) << 6) + d] = f2bf(v);
          }
        }
      }
    }
  }
}

// ---------------- causal flash attention, 8 waves x 32 q-rows, LDS-staged K/V ----------------
// q,k: [B][H][T][D] bf16 (q pre-scaled by log2e/sqrt(D)) ; vp: [B][H][D][T] bf16 key-permuted ;
// y: [B][T][C] bf16. Swapped QK^T (S^T = K Q^T) and swapped PV (O^T = Vp P^T) keep softmax
// fully lane-local; P^T B-fragments come straight from S^T accumulator registers.
__global__ __launch_bounds__(512, 4)
void attn3(const unsigned short* __restrict__ q,
           const unsigned short* __restrict__ k,
           const unsigned short* __restrict__ vp,
           unsigned short* __restrict__ y)
{
  __shared__ unsigned short lsK[2][64 * 64];
  __shared__ unsigned short lsV[2][64 * 64];
  const int tid  = threadIdx.x;
  const int wave = tid >> 6;
  const int lane = tid & 63;
  const int col  = lane & 31;   // query (or K/V row) index within 32
  const int hi   = lane >> 5;
  const int bh = blockIdx.y;
  const int b = bh >> 4, h = bh & 15;
  const int qt = gridDim.x - 1 - blockIdx.x;   // longest-first
  const int q0 = qt * 256 + wave * 32;
  const unsigned short* qh = q  + (size_t)bh * T_ * D_;
  const unsigned short* kh = k  + (size_t)bh * T_ * D_;
  const unsigned short* vh = vp + (size_t)bh * D_ * T_;

  // staging source (inverse-swizzled): thread t -> LDS linear byte t*16
  const int srow = tid >> 3;
  const int srcE = ((tid & 7) * 8) ^ ((srow & 7) << 3);
  const unsigned short* ksrc = kh + srow * D_ + srcE;   // + s*64*D_ per step
  const unsigned short* vsrc = vh + srow * T_ + srcE;   // + s*64 per step

  // Q B-fragments: bqf[ks] supplies Q[q0+col][ks*16 + hi*8 + e]
  bf16x8 bqf[4];
  {
    const unsigned short* qrow = qh + (size_t)(q0 + col) * D_ + hi * 8;
    #pragma unroll
    for (int ks = 0; ks < 4; ++ks) bqf[ks] = *(const bf16x8*)(qrow + ks * 16);
  }

  f32x16 ot0 = {}, ot1 = {};
  float m = -INFINITY, l = 0.f;
  const int swz = (col & 7) << 4;
  const int nsteps = (qt + 1) * 4;

  // prologue: stage tile 0
  gload_lds16(ksrc, &lsK[0][tid * 8]);
  gload_lds16(vsrc, &lsV[0][tid * 8]);
  __syncthreads();

  for (int s = 0; s < nsteps; ++s) {
    const int n0 = s * 64;
    const unsigned short* baseK = (s & 1) ? lsK[1] : lsK[0];
    const unsigned short* baseV = (s & 1) ? lsV[1] : lsV[0];
    if (s + 1 < nsteps) {
      unsigned short* nK = (s & 1) ? &lsK[0][tid * 8] : &lsK[1][tid * 8];
      unsigned short* nV = (s & 1) ? &lsV[0][tid * 8] : &lsV[1][tid * 8];
      gload_lds16(ksrc + (size_t)(s + 1) * 64 * D_, nK);
      gload_lds16(vsrc + (s + 1) * 64, nV);
    }
    if (n0 <= q0 + 31) {
      const bool two = (n0 < q0);   // upper 32 keys live?
      // ---- QK^T ----
      f32x16 st0 = {};
      f32x16 st1;
      {
        const char* kb0 = (const char*)baseK + col * 128;
        #pragma unroll
        for (int ks = 0; ks < 4; ++ks) {
          bf16x8 ak = *(const bf16x8*)(kb0 + ((ks * 32 + hi * 16) ^ swz));
          st0 = __builtin_amdgcn_mfma_f32_32x32x16_bf16(ak, bqf[ks], st0, 0, 0, 0);
        }
        if (two) {
          f32x16 a = {};
          const char* kb1 = kb0 + 32 * 128;
          #pragma unroll
          for (int ks = 0; ks < 4; ++ks) {
            bf16x8 ak = *(const bf16x8*)(kb1 + ((ks * 32 + hi * 16) ^ swz));
            a = __builtin_amdgcn_mfma_f32_32x32x16_bf16(ak, bqf[ks], a, 0, 0, 0);
          }
          st1 = a;
        }
      }
      // ---- causal mask (diagonal tiles only) ----
      if (n0 + 63 > q0) {
        #pragma unroll
        for (int r = 0; r < 16; ++r) {
          int key0 = n0 + (r & 3) + 8 * (r >> 2) + 4 * hi;
          if (key0 > q0 + col) st0[r] = -INFINITY;
          if (two) { if (key0 + 32 > q0 + col) st1[r] = -INFINITY; }
        }
      }
      // ---- online softmax (lane-local, exp2 domain, defer-max THR=8) ----
      float mm = st0[0];
      #pragma unroll
      for (int r = 1; r < 16; ++r) mm = fmaxf(mm, st0[r]);
      if (two) {
        #pragma unroll
        for (int r = 0; r < 16; ++r) mm = fmaxf(mm, st1[r]);
      }
      mm = fmaxf(mm, __shfl_xor(mm, 32));
      if (!__all(mm <= m + 8.f)) {
        float mnew = fmaxf(m, mm);
        float corr = exp2f(m - mnew);
        m = mnew;
        l *= corr;
        #pragma unroll
        for (int r = 0; r < 16; ++r) { ot0[r] *= corr; ot1[r] *= corr; }
      }
      bf16x8 pf[4];
      float psum = 0.f;
      #pragma unroll
      for (int half = 0; half < 2; ++half) {
        bf16x8 w;
        #pragma unroll
        for (int e = 0; e < 8; ++e) {
          float pv = exp2f(st0[half * 8 + e] - m);
          psum += pv;
          w[e] = (__bf16)pv;
        }
        pf[half] = w;
      }
      if (two) {
        #pragma unroll
        for (int half = 0; half < 2; ++half) {
          bf16x8 w;
          #pragma unroll
          for (int e = 0; e < 8; ++e) {
            float pv = exp2f(st1[half * 8 + e] - m);
            psum += pv;
            w[e] = (__bf16)pv;
          }
          pf[2 + half] = w;
        }
      }
      psum += __shfl_xor(psum, 32);
      l += psum;
      // ---- PV: O^T += Vp · P^T ----
      {
        const char* vb0 = (const char*)baseV + col * 128;
        const char* vb1 = vb0 + 32 * 128;
        #pragma unroll
        for (int ks = 0; ks < 2; ++ks) {
          bf16x8 av0 = *(const bf16x8*)(vb0 + ((ks * 32 + hi * 16) ^ swz));
          bf16x8 av1 = *(const bf16x8*)(vb1 + ((ks * 32 + hi * 16) ^ swz));
          ot0 = __builtin_amdgcn_mfma_f32_32x32x16_bf16(av0, pf[ks], ot0, 0, 0, 0);
          ot1 = __builtin_amdgcn_mfma_f32_32x32x16_bf16(av1, pf[ks], ot1, 0, 0, 0);
        }
        if (two) {
          #pragma unroll
          for (int ks = 2; ks < 4; ++ks) {
            bf16x8 av0 = *(const bf16x8*)(vb0 + ((ks * 32 + hi * 16) ^ swz));
            bf16x8 av1 = *(const bf16x8*)(vb1 + ((ks * 32 + hi * 16) ^ swz));
            ot0 = __builtin_amdgcn_mfma_f32_32x32x16_bf16(av0, pf[ks], ot0, 0, 0, 0);
            ot1 = __builtin_amdgcn_mfma_f32_32x32x16_bf16(av1, pf[ks], ot1, 0, 0, 0);
          }
        }
      }
    }
    __syncthreads();
  }

  // ---- normalize + store y[B][T][C] ----
  float inv = 1.f / l;
  unsigned short* yrow = y + ((size_t)b * T_ + q0 + col) * C_ + h * D_;
  #pragma unroll
  for (int a = 0; a < 4; ++a) {
    ushort4 o4;
    o4.x = f2bf(ot0[4 * a + 0] * inv);
    o4.y = f2bf(ot0[4 * a + 1] * inv);
    o4.z = f2bf(ot0[4 * a + 2] * inv);
    o4.w = f2bf(ot0[4 * a + 3] * inv);
    *(ushort4*)(yrow + 8 * a + 4 * hi) = o4;
  }
  #pragma unroll
  for (int a = 0; a < 4; ++a) {
    ushort4 o4;
    o4.x = f2bf(ot1[4 * a + 0] * inv);
    o4.y = f2bf(ot1[4 * a + 1] * inv);
    o4.z = f2bf(ot1[4 * a + 2] * inv);
    o4.w = f2bf(ot1[4 * a + 3] * inv);
    *(ushort4*)(yrow + 32 + 8 * a + 4 * hi) = o4;
  }
}

extern "C" void kernel_launch(void* const* d_in, const int* in_sizes, int n_in,
                              void* d_out, int out_size, void* d_ws, size_t ws_size,
                              hipStream_t stream) {
  const float* x  = (const float*)d_in[0];
  const float* Wq = (const float*)d_in[1];
  const float* bq = (const float*)d_in[2];
  const float* Wk = (const float*)d_in[3];
  const float* bk = (const float*)d_in[4];
  const float* Wv = (const float*)d_in[5];
  const float* bv = (const float*)d_in[6];
  const float* Wp = (const float*)d_in[7];
  const float* bp = (const float*)d_in[8];
  float* out = (float*)d_out;

  char* ws = (char*)d_ws;
  unsigned short* xb  = (unsigned short*)ws; ws += (size_t)M_ * C_ * 2;
  unsigned short* wqt = (unsigned short*)ws; ws += (size_t)C_ * C_ * 2;
  unsigned short* wkt = (unsigned short*)ws; ws += (size_t)C_ * C_ * 2;
  unsigned short* wvt = (unsigned short*)ws; ws += (size_t)C_ * C_ * 2;
  unsigned short* wpt = (unsigned short*)ws; ws += (size_t)C_ * C_ * 2;
  unsigned short* qb  = (unsigned short*)ws; ws += (size_t)M_ * C_ * 2;
  unsigned short* kb  = (unsigned short*)ws; ws += (size_t)M_ * C_ * 2;
  unsigned short* vtb = (unsigned short*)ws; ws += (size_t)M_ * C_ * 2;
  unsigned short* yb  = (unsigned short*)ws; ws += (size_t)M_ * C_ * 2;

  cvt_f32_bf16<<<dim3((M_ * C_ / 4 + 255) / 256), dim3(256), 0, stream>>>(x, xb, M_ * C_ / 4);
  transpose_cvt<<<dim3(32, 32, 4), dim3(32, 8), 0, stream>>>(Wq, Wk, Wv, Wp, wqt, wkt, wvt, wpt);

  dim3 ggrid(C_ / 128, M_ / 128);
  const float qscale = 0.125f * 1.4426950408889634f;  // 1/sqrt(64) * log2(e): exp2-domain softmax
  gemm_bf16<0><<<ggrid, dim3(256), 0, stream>>>(xb, wqt, bq, qb, C_, C_, qscale);
  gemm_bf16<0><<<ggrid, dim3(256), 0, stream>>>(xb, wkt, bk, kb, C_, C_, 1.f);
  gemm_bf16<1><<<ggrid, dim3(256), 0, stream>>>(xb, wvt, bv, vtb, C_, C_, 1.f);

  attn3<<<dim3(T_ / 256, B_ * H_), dim3(512), 0, stream>>>(qb, kb, vtb, yb);

  gemm_bf16<2><<<ggrid, dim3(256), 0, stream>>>(yb, wpt, bp, out, C_, C_, 1.f);
}